// Round 10
// baseline (664.775 us; speedup 1.0000x reference)
//
#include <hip/hip_runtime.h>
#include <hip/hip_bf16.h>

// ================= problem constants =================
#define NNODES 10000
#define EEDGES 160000
#define HD     512
#define OUTD   128
#define NLAYERS 3
#define MP     10112           // NNODES padded to 79*128
#define KTP    10240           // transposed-layout node-dim pad (16*640)

#define ACT_NONE 0
#define ACT_RELU 1
#define ACT_ELU1 2

typedef __attribute__((ext_vector_type(8))) short bf16x8;
typedef __attribute__((ext_vector_type(4))) float f32x4;

__device__ __forceinline__ void gload16(const void* g, void* l) {
  __builtin_amdgcn_global_load_lds(
      (const __attribute__((address_space(1))) void*)g,
      (__attribute__((address_space(3))) void*)l, 16, 0, 0);
}

__device__ __forceinline__ void unp8(uint4 v, float* f) {
  const ushort* u = (const ushort*)&v;
#pragma unroll
  for (int j = 0; j < 8; ++j) f[j] = __uint_as_float(((unsigned)u[j]) << 16);
}

__device__ __forceinline__ ushort f2bu(float f) {
  __hip_bfloat16 h = __float2bfloat16(f);
  return *reinterpret_cast<ushort*>(&h);
}

__device__ __forceinline__ float elu1f(float v) {
  return (v > 0.f) ? (v + 1.0f) : __expf(v);
}

// ================= setup mega-kernel: init + castx + wtrans =================
// block ranges: [0,B0) init, [B0,B0+B1) castx, [B0+B1, ...) wtrans (17 z-slices).
// probe stays a separate dispatch (flag zero must precede its atomicOr).
#define INIT_N (3 * HD * HD + NNODES + 1 + 512 * 120 * 2)
#define B0 ((INIT_N + 255) / 256)
#define B1 ((int)((long)MP * HD / 8 / 256))
#define B2 (17 * 256)
__global__ __launch_bounds__(256) void setup_k(
    int* cnt, int* flag, float* kvf, __hip_bfloat16* kT, __hip_bfloat16* vT,
    const float* x, __hip_bfloat16* xb,
    const float* W_in, const float* Wq, const float* Wk, const float* Wv,
    const float* Wo, const float* W_gcn, const float* W_mix, const float* W_cls,
    __hip_bfloat16* WT, __hip_bfloat16* WMT, __hip_bfloat16* WCT)
{
  __shared__ float t[32][33];
  int b = blockIdx.x;
  if (b < B0) {
    int i = b * 256 + threadIdx.x;
    if (i < 3 * HD * HD) { kvf[i] = 0.f; return; }
    i -= 3 * HD * HD;
    if (i < NNODES) { cnt[i] = 0; return; }
    i -= NNODES;
    if (i == 0) { *flag = 0; return; }
    i -= 1;
    if (i < 512 * 120 * 2) {
      int bb = i / (512 * 120);
      int r = (i % (512 * 120)) / 120;
      int c = (i % 120);
      uint* T = (uint*)(bb == 0 ? kT : vT);
      T[((long)r * KTP + NNODES) / 2 + c] = 0u;
    }
    return;
  }
  b -= B0;
  if (b < B1) {
    long i = (long)b * 256 + threadIdx.x;
    long base = i * 8;
    int row = (int)(base >> 9);
    ushort o[8];
    if (row < NNODES) {
      float4 a = *(const float4*)(x + base);
      float4 c = *(const float4*)(x + base + 4);
      float f[8] = {a.x, a.y, a.z, a.w, c.x, c.y, c.z, c.w};
#pragma unroll
      for (int j = 0; j < 8; ++j) o[j] = f2bu(f[j]);
    } else {
#pragma unroll
      for (int j = 0; j < 8; ++j) o[j] = 0;
    }
    *(uint4*)((ushort*)xb + base) = *(const uint4*)o;
    return;
  }
  b -= B1;
  // wtrans role: z=0 W_in; 1..9 {Wq,Wk,Wv}; 10..12 Wo; 13 W_gcn; 14/15 W_mix->WMT; 16 W_cls->WCT
  int z = b >> 8;
  int rem = b & 255;
  int by = rem >> 4, bx = rem & 15;
  const float* src;
  __hip_bfloat16* out;
  int ldout = 512, koff = 0, ldsrc = 512;
  if (z == 0) { src = W_in; out = WT; }
  else if (z <= 9) {
    int l = (z - 1) / 3, w = (z - 1) % 3;
    src = (w == 0 ? Wq : w == 1 ? Wk : Wv) + (long)l * 262144;
    out = WT + (long)z * 262144;
  } else if (z <= 12) { src = Wo + (long)(z - 10) * 262144; out = WT + (long)z * 262144; }
  else if (z == 13) { src = W_gcn; out = WT + 13L * 262144; }
  else if (z <= 15) { src = W_mix + (long)(z - 14) * 262144; out = WMT; ldout = 1024; koff = (z - 14) * 512; }
  else {
    if (bx >= 4) return;              // W_cls has only 128 cols
    src = W_cls; out = WCT; ldsrc = 128;
  }
  int r0 = by * 32, c0 = bx * 32;
  int tx = threadIdx.x & 31, ty = threadIdx.x >> 5;
#pragma unroll
  for (int i = 0; i < 32; i += 8) t[ty + i][tx] = src[(long)(r0 + ty + i) * ldsrc + c0 + tx];
  __syncthreads();
#pragma unroll
  for (int i = 0; i < 32; i += 8)
    out[(long)(c0 + ty + i) * ldout + koff + r0 + tx] = __float2bfloat16(t[tx][ty + i]);
}

// ================= edge-index width probe (wave-coalesced atomic) =================
__global__ void probe_i64_k(const void* ei, int* flag, int E_) {
  int i = blockIdx.x * blockDim.x + threadIdx.x;
  bool nz = (i < E_) && (((const int*)ei)[2 * i + 1] != 0);
  unsigned long long m = __ballot(nz);
  if ((threadIdx.x & 63) == 0 && m) atomicOr(flag, 1);  // int32 layout detected
}
__device__ inline void load_edge(const void* ei, int is_i32, int e, int E_, int& s, int& d) {
  if (is_i32) { s = ((const int*)ei)[e]; d = ((const int*)ei)[E_ + e]; }
  else { s = (int)((const long long*)ei)[e]; d = (int)((const long long*)ei)[E_ + e]; }
}

// ================= bf16 MFMA GEMM (m97 structure, BK=64, XCD swizzle) =================
// C = epi(A[M,lda] @ Bt[N,ldb]^T), Bt row-major [N][K].
// 128x128 tile, BK=64, 4 waves (2x2), wave tile 64x64. LDS rows 128B, XOR
// bank-swizzle applied BOTH sides (pre-swizzled global source + swizzled
// ds_read) per rule #21. TQKV epilogue eps UNIONED with As/Bs.
// KSUM: kv-dispatch carries 32 extra blocks (z>=16) computing aux[i]=rowsum(A[i]).
template<int ACT, int HAS_BIAS, int HAS_SCALE, int OUTF, int OUTB, int ATOMIC, int TQKV, int KSUM>
__global__ __launch_bounds__(256) void mgemm(
    const __hip_bfloat16* __restrict__ A, const __hip_bfloat16* __restrict__ Bt,
    const float* __restrict__ bias, const float* __restrict__ rowscale,
    float* __restrict__ Cf, __hip_bfloat16* __restrict__ Cb,
    __hip_bfloat16* __restrict__ kTp, __hip_bfloat16* __restrict__ vTp,
    float* __restrict__ aux,
    int M, int lda, int ldb, int ldc, int ldcb, int Ksz)
{
  if (KSUM) {
    if (blockIdx.z >= 16) {
      // ksum role: 32 blocks x 4 waves, 4 rows/wave over 512 rows of A (=kT)
      int role = (blockIdx.z - 16) * 16 + blockIdx.y * 4 + blockIdx.x;
      int wv = threadIdx.x >> 6, lane = threadIdx.x & 63;
#pragma unroll
      for (int rr = 0; rr < 4; ++rr) {
        int i = role * 16 + wv * 4 + rr;
        const ushort* kr = (const ushort*)A + (long)i * lda;
        float s = 0.f;
        for (int off = lane * 8; off < NNODES; off += 512) {
          uint4 v = *(const uint4*)(kr + off);
          float f[8]; unp8(v, f);
#pragma unroll
          for (int j = 0; j < 8; ++j) s += f[j];
        }
#pragma unroll
        for (int o = 32; o > 0; o >>= 1) s += __shfl_down(s, o);
        if (lane == 0) aux[i] = s;
      }
      return;
    }
  }
  // As: [0,16384) rows 128B; Bs: [16384,32768); TQKV eps overlaps from 0
  __shared__ __align__(16) char smem[TQKV ? 35072 : 32768];

  // bijective XCD-aware swizzle (m204)
  int nwg = gridDim.x * gridDim.y;
  int orig = blockIdx.y * gridDim.x + blockIdx.x;
  int qq = nwg >> 3, rr8 = nwg & 7;
  int xcd = orig & 7, idx = orig >> 3;
  int wg = (xcd < rr8 ? xcd * (qq + 1) : rr8 * (qq + 1) + (xcd - rr8) * qq) + idx;
  int bx = wg % gridDim.x, by = wg / gridDim.x;

  int tid = threadIdx.x;
  int lane = tid & 63;
  int wave = tid >> 6;
  int wm = wave >> 1, wn = wave & 1;
  int row0 = by * 128;
  int col0 = bx * 128;
  int koff = blockIdx.z * Ksz;
  int srow8 = lane >> 3;               // 0..7
  int sb = ((lane & 7) * 16) ^ (srow8 << 4);  // pre-swizzled source byte

  f32x4 acc[4][4];
#pragma unroll
  for (int i = 0; i < 4; ++i)
#pragma unroll
    for (int j = 0; j < 4; ++j) acc[i][j] = f32x4{0.f, 0.f, 0.f, 0.f};

  int r16 = lane & 15;
  int kg = (lane >> 4) * 16;
  int rsw = (r16 & 7) << 4;

  for (int k0 = koff; k0 < koff + Ksz; k0 += 64) {
#pragma unroll
    for (int j = 0; j < 4; ++j) {
      int rbase = wave * 32 + j * 8;
      const char* ga = (const char*)(A + (long)(row0 + rbase + srow8) * lda + k0) + sb;
      gload16(ga, smem + rbase * 128);
      const char* gb = (const char*)(Bt + (long)(col0 + rbase + srow8) * ldb + k0) + sb;
      gload16(gb, smem + 16384 + rbase * 128);
    }
    __syncthreads();
#pragma unroll
    for (int s = 0; s < 2; ++s) {
      bf16x8 af[4], bfr[4];
      int off = ((s * 64 + kg) ^ rsw);
#pragma unroll
      for (int i = 0; i < 4; ++i)
        af[i] = *(const bf16x8*)(smem + (wm * 64 + i * 16 + r16) * 128 + off);
#pragma unroll
      for (int i = 0; i < 4; ++i)
        bfr[i] = *(const bf16x8*)(smem + 16384 + (wn * 64 + i * 16 + r16) * 128 + off);
#pragma unroll
      for (int i = 0; i < 4; ++i)
#pragma unroll
        for (int j = 0; j < 4; ++j)
          acc[i][j] = __builtin_amdgcn_mfma_f32_16x16x32_bf16(af[i], bfr[j], acc[i][j], 0, 0, 0);
    }
    __syncthreads();
  }

  // D frag: col = lane&15, row = (lane>>4)*4 + r  [m89/m91-verified]
  int rg = (lane >> 4) * 4;
  if (TQKV) {
    ushort* eps = (ushort*)smem;
    int colg = col0 + wn * 64;
    int g = colg >> 9;                // block-uniform (128-tile within 512-group)
    int cbase = col0 & 511;
#pragma unroll
    for (int i = 0; i < 4; ++i) {
#pragma unroll
      for (int j = 0; j < 4; ++j) {
        int c_l = wn * 64 + j * 16 + r16;
        int row_l = wm * 64 + i * 16 + rg;
        if (g == 0) {
#pragma unroll
          for (int r = 0; r < 4; ++r)
            eps[(row_l + r) * 136 + c_l] = f2bu(elu1f(acc[i][j][r]));
        } else {
          ushort4 o;
          o.x = f2bu(g == 1 ? elu1f(acc[i][j][0]) : acc[i][j][0]);
          o.y = f2bu(g == 1 ? elu1f(acc[i][j][1]) : acc[i][j][1]);
          o.z = f2bu(g == 1 ? elu1f(acc[i][j][2]) : acc[i][j][2]);
          o.w = f2bu(g == 1 ? elu1f(acc[i][j][3]) : acc[i][j][3]);
          *(ushort4*)&eps[c_l * 136 + row_l] = o;
        }
      }
    }
    __syncthreads();
    int l16 = tid & 15, cw = tid >> 4;
    if (g == 0) {
#pragma unroll
      for (int rr = cw; rr < 128; rr += 16) {
        int node = row0 + rr;
        if (node < NNODES)
          *(uint4*)((ushort*)Cb + (long)node * ldcb + cbase + l16 * 8) =
              *(const uint4*)&eps[rr * 136 + l16 * 8];
      }
    } else {
      ushort* T = (ushort*)(g == 1 ? kTp : vTp);
      int node0 = row0 + l16 * 8;
      if (node0 < NNODES) {
#pragma unroll
        for (int cc = cw; cc < 128; cc += 16)
          *(uint4*)(T + (long)(cbase + cc) * KTP + node0) = *(const uint4*)&eps[cc * 136 + l16 * 8];
      }
    }
    return;
  }
#pragma unroll
  for (int i = 0; i < 4; ++i) {
#pragma unroll
    for (int j = 0; j < 4; ++j) {
      int col = col0 + wn * 64 + j * 16 + r16;
#pragma unroll
      for (int r = 0; r < 4; ++r) {
        int row = row0 + wm * 64 + i * 16 + rg + r;
        if (row >= M) continue;
        float v = acc[i][j][r];
        if (ATOMIC) { atomicAdd(&Cf[(long)row * ldc + col], v); continue; }
        if (HAS_SCALE) v *= rowscale[row];
        if (HAS_BIAS) v += bias[col];
        if (ACT == ACT_RELU) v = fmaxf(v, 0.f);
        if (ACT == ACT_ELU1) v = elu1f(v);
        if (OUTF) Cf[(long)row * ldc + col] = v;
        if (OUTB) Cb[(long)row * ldcb + col] = __float2bfloat16(v);
      }
    }
  }
}

// ===== merged: cast8 (kvf->kvb, blocks 0..127) + z (blocks 128..2627) =====
__global__ __launch_bounds__(256) void cast_z_k(
    const float* __restrict__ kvf, __hip_bfloat16* __restrict__ kvb,
    const __hip_bfloat16* __restrict__ qb, const float* __restrict__ ksum,
    float* __restrict__ z)
{
  int b = blockIdx.x;
  if (b < 128) {
    int i = b * 256 + threadIdx.x;    // 32768 groups of 8 = 512*512/8
    float4 a = ((const float4*)kvf)[2 * i], c = ((const float4*)kvf)[2 * i + 1];
    float f[8] = {a.x, a.y, a.z, a.w, c.x, c.y, c.z, c.w};
    ushort o[8];
#pragma unroll
    for (int j = 0; j < 8; ++j) o[j] = f2bu(f[j]);
    *(uint4*)((ushort*)kvb + (long)i * 8) = *(const uint4*)o;
    return;
  }
  long gid = (long)(b - 128) * 256 + threadIdx.x;
  int row = (int)(gid >> 6), lane = (int)(gid & 63);
  if (row >= NNODES) return;
  uint4 qv = *(const uint4*)((const ushort*)qb + (long)row * HD + lane * 8);
  float f[8]; unp8(qv, f);
  const float* kk = ksum + lane * 8;
  float s = 0.f;
#pragma unroll
  for (int j = 0; j < 8; ++j) s += f[j] * kk[j];
#pragma unroll
  for (int o = 32; o > 0; o >>= 1) s += __shfl_down(s, o);
  if (lane == 0) z[row] = 1.0f / fmaxf(s, 1e-6f);
}

// ====== hg = LN(hg + h[bf16]); f32 -> hg, bf16 -> hgcat[:,0:512] (ld 1024) ======
__global__ __launch_bounds__(256) void ln_res_k(float* __restrict__ hg,
                                                const __hip_bfloat16* __restrict__ hb,
                                                __hip_bfloat16* __restrict__ hgcat) {
  int wid = (blockIdx.x * 256 + threadIdx.x) >> 6;
  int lane = threadIdx.x & 63;
  if (wid >= NNODES) return;
  float* row = hg + (long)wid * HD + lane * 8;
  uint4 hv = *(const uint4*)((const ushort*)hb + (long)wid * HD + lane * 8);
  float hf[8]; unp8(hv, hf);
  float4 p0 = *(const float4*)row, p1 = *(const float4*)(row + 4);
  float a[8] = {p0.x + hf[0], p0.y + hf[1], p0.z + hf[2], p0.w + hf[3],
                p1.x + hf[4], p1.y + hf[5], p1.z + hf[6], p1.w + hf[7]};
  float s = 0.f;
#pragma unroll
  for (int j = 0; j < 8; ++j) s += a[j];
#pragma unroll
  for (int o = 1; o < 64; o <<= 1) s += __shfl_xor(s, o);
  float mean = s * (1.0f / HD);
  float vs = 0.f;
#pragma unroll
  for (int j = 0; j < 8; ++j) { a[j] -= mean; vs += a[j] * a[j]; }
#pragma unroll
  for (int o = 1; o < 64; o <<= 1) vs += __shfl_xor(vs, o);
  float inv = rsqrtf(vs * (1.0f / HD) + 1e-5f);
  ushort ob[8];
#pragma unroll
  for (int j = 0; j < 8; ++j) { a[j] *= inv; ob[j] = f2bu(a[j]); }
  *(float4*)row = make_float4(a[0], a[1], a[2], a[3]);
  *(float4*)(row + 4) = make_float4(a[4], a[5], a[6], a[7]);
  *(uint4*)((ushort*)hgcat + (long)wid * 1024 + lane * 8) = *(const uint4*)ob;
}

// ================= GCN: CSR build + gather =================
__global__ void cnt_k(const void* ei, const int* flag, int* cnt, int E_) {
  int e = blockIdx.x * blockDim.x + threadIdx.x;
  if (e >= E_) return;
  int s, d; load_edge(ei, *flag, e, E_, s, d);
  atomicAdd(&cnt[d], 1);
}
__global__ __launch_bounds__(256) void scan_k(const int* __restrict__ cnt, int* __restrict__ rowptr,
                                              int* __restrict__ cursor, float* __restrict__ dis) {
  __shared__ int ps[256];
  int t = threadIdx.x;
  int lo = t * 40, hi = min(lo + 40, NNODES);
  int s = 0;
  for (int i = lo; i < hi; ++i) s += cnt[i];
  ps[t] = s;
  __syncthreads();
  for (int o = 1; o < 256; o <<= 1) {
    int v = (t >= o) ? ps[t - o] : 0;
    __syncthreads();
    ps[t] += v;
    __syncthreads();
  }
  int run = (t == 0) ? 0 : ps[t - 1];
  for (int i = lo; i < hi; ++i) {
    rowptr[i] = run; cursor[i] = run;
    dis[i] = rsqrtf((float)cnt[i] + 1.0f);
    run += cnt[i];
  }
  if (t == 255) rowptr[NNODES] = run;
}
__global__ void csrfill_k(const void* ei, const int* flag, int* cursor, int* csr, int E_) {
  int e = blockIdx.x * blockDim.x + threadIdx.x;
  if (e >= E_) return;
  int s, d; load_edge(ei, *flag, e, E_, s, d);
  int pos = atomicAdd(&cursor[d], 1);
  csr[pos] = s;
}
// wave per dst: h_graph[d] = relu(sum_src xw[src]*dis[s]*dis[d] + xw[d]*dis[d]^2 + b)
__global__ __launch_bounds__(256) void gcn_gather_k(
    const __hip_bfloat16* __restrict__ xwb, const int* __restrict__ rowptr,
    const int* __restrict__ csr, const float* __restrict__ dis,
    const float* __restrict__ bgcn, __hip_bfloat16* __restrict__ hgcat)
{
  int wid = (blockIdx.x * 256 + threadIdx.x) >> 6;
  int lane = threadIdx.x & 63;
  if (wid >= NNODES) return;
  int d = wid;
  float dd = dis[d];
  float acc[8], f[8], f2[8];
  uint4 v = *(const uint4*)((const ushort*)xwb + (long)d * HD + lane * 8);
  unp8(v, f);
#pragma unroll
  for (int j = 0; j < 8; ++j) acc[j] = f[j] * dd * dd;
  int e0 = rowptr[d], e1 = rowptr[d + 1];
  int e = e0;
  for (; e + 1 < e1; e += 2) {
    int s0 = csr[e], s1 = csr[e + 1];
    float w0 = dis[s0] * dd, w1 = dis[s1] * dd;
    uint4 xv0 = *(const uint4*)((const ushort*)xwb + (long)s0 * HD + lane * 8);
    uint4 xv1 = *(const uint4*)((const ushort*)xwb + (long)s1 * HD + lane * 8);
    unp8(xv0, f); unp8(xv1, f2);
#pragma unroll
    for (int j = 0; j < 8; ++j) acc[j] = fmaf(f[j], w0, fmaf(f2[j], w1, acc[j]));
  }
  if (e < e1) {
    int sN = csr[e];
    float w = dis[sN] * dd;
    uint4 xv = *(const uint4*)((const ushort*)xwb + (long)sN * HD + lane * 8);
    unp8(xv, f);
#pragma unroll
    for (int j = 0; j < 8; ++j) acc[j] = fmaf(f[j], w, acc[j]);
  }
  const float* bb = bgcn + lane * 8;
  ushort o[8];
#pragma unroll
  for (int j = 0; j < 8; ++j) o[j] = f2bu(fmaxf(acc[j] + bb[j], 0.f));
  *(uint4*)((ushort*)hgcat + (long)d * 1024 + 512 + lane * 8) = *(const uint4*)o;
}

// ================= host launcher =================
extern "C" void kernel_launch(void* const* d_in, const int* in_sizes, int n_in,
                              void* d_out, int out_size, void* d_ws, size_t ws_size,
                              hipStream_t stream) {
  const float* x     = (const float*)d_in[0];
  const void*  ei    = d_in[1];
  const float* W_in  = (const float*)d_in[2];
  const float* b_in  = (const float*)d_in[3];
  const float* Wq    = (const float*)d_in[4];
  const float* Wk    = (const float*)d_in[5];
  const float* Wv    = (const float*)d_in[6];
  const float* Wo    = (const float*)d_in[7];
  const float* bo    = (const float*)d_in[8];
  const float* W_gcn = (const float*)d_in[9];
  const float* b_gcn = (const float*)d_in[10];
  const float* W_mix = (const float*)d_in[11];
  const float* b_mix = (const float*)d_in[12];
  const float* W_cls = (const float*)d_in[13];
  const float* b_cls = (const float*)d_in[14];
  float* out = (float*)d_out;

  // ---- workspace layout (~90 MB) ----
  char* p = (char*)d_ws;
  __hip_bfloat16* WT  = (__hip_bfloat16*)p; p += 14L * 262144 * 2;
  __hip_bfloat16* WMT = (__hip_bfloat16*)p; p += 512L * 1024 * 2;
  __hip_bfloat16* WCT = (__hip_bfloat16*)p; p += 128L * 512 * 2;
  float* hg = (float*)p; p += (long)MP * HD * 4;
  __hip_bfloat16* hgcat = (__hip_bfloat16*)p; p += (long)MP * 1024 * 2;
  __hip_bfloat16* qb = (__hip_bfloat16*)p; p += (long)MP * HD * 2;   // xb/xwb alias
  __hip_bfloat16* vT = (__hip_bfloat16*)p; p += 512L * KTP * 2;
  __hip_bfloat16* kT = (__hip_bfloat16*)p; p += 512L * KTP * 2;     // hb/hmixb alias
  float* kvf = (float*)p; p += 3L * 512 * 512 * 4;                   // 3 split-K slots
  __hip_bfloat16* kvb  = (__hip_bfloat16*)p; p += 512L * 512 * 2;
  __hip_bfloat16* kvoT = (__hip_bfloat16*)p; p += 512L * 512 * 2;
  float* ksum = (float*)p; p += 3L * 512 * 4;                        // 3 slots
  float* zb   = (float*)p; p += (long)MP * 4;
  int* cnt    = (int*)p; p += 40000;
  int* rowptr = (int*)p; p += 40016;
  int* cursor = (int*)p; p += 40000;
  float* dis  = (float*)p; p += 40000;
  int* csr    = (int*)p; p += 640000;
  int* flag   = (int*)p; p += 4;

  __hip_bfloat16* xb    = qb;     // input cast (dead after x0 GEMM)
  __hip_bfloat16* xwb   = qb;     // GCN xw (dead after gather)
  __hip_bfloat16* hb    = kT;     // attn h bf16 (kT dead after kv GEMM)
  __hip_bfloat16* hmixb = kT;     // mix out (after last layer)

  dim3 blk(256);
  dim3 gG(4, MP / 128);           // N=512 GEMMs
  dim3 gQKV(12, MP / 128);        // N=1536 fused
  dim3 gKV(4, 4, 18);             // kv split-K=16 x 640 + 32 ksum-role blocks
  dim3 gS(4, 4);                  // 512x512 kvoT GEMM
  dim3 gCls(1, MP / 128);

  // ---- setup: one mega-kernel (init+castx+wtrans), then probe ----
  setup_k<<<B0 + B1 + B2, blk, 0, stream>>>(cnt, flag, kvf, kT, vT, x, xb,
                                            W_in, Wq, Wk, Wv, Wo, W_gcn, W_mix, W_cls,
                                            WT, WMT, WCT);
  probe_i64_k<<<(EEDGES + 255) / 256, 256, 0, stream>>>(ei, flag, EEDGES);

  // x0 = relu(x@W_in+b): f32 -> hg, bf16 -> hgcat[:,0:512]
  mgemm<ACT_RELU, 1, 0, 1, 1, 0, 0, 0><<<gG, blk, 0, stream>>>(
      xb, WT, b_in, nullptr, hg, hgcat, nullptr, nullptr, nullptr,
      NNODES, HD, HD, HD, 1024, HD);

  // ---- GCN branch ----
  mgemm<ACT_NONE, 0, 0, 0, 1, 0, 0, 0><<<gG, blk, 0, stream>>>(
      hgcat, WT + 13L * 262144, nullptr, nullptr, nullptr, xwb, nullptr, nullptr, nullptr,
      NNODES, 1024, HD, HD, HD, HD);
  cnt_k<<<(EEDGES + 255) / 256, 256, 0, stream>>>(ei, flag, cnt, EEDGES);
  scan_k<<<1, 256, 0, stream>>>(cnt, rowptr, cursor, dis);
  csrfill_k<<<(EEDGES + 255) / 256, 256, 0, stream>>>(ei, flag, cursor, csr, EEDGES);
  gcn_gather_k<<<2500, blk, 0, stream>>>(xwb, rowptr, csr, dis, b_gcn, hgcat);

  // ---- attention layers ----
  for (int l = 0; l < NLAYERS; ++l) {
    const __hip_bfloat16* BtQKV = WT + (long)(1 + 3 * l) * 262144;   // [1536][512]
    const __hip_bfloat16* WoT   = WT + (long)(10 + l) * 262144;      // wo^T [512][512]
    float* kvfl  = kvf + (long)l * HD * HD;
    float* ksuml = ksum + (long)l * HD;

    // fused q/k/v: q->qb (elu1), k->kT[c][n] (elu1), v->vT[c][n]
    mgemm<ACT_NONE, 0, 0, 0, 0, 0, 1, 0><<<gQKV, blk, 0, stream>>>(
        hgcat, BtQKV, nullptr, nullptr, nullptr, qb, kT, vT, nullptr,
        NNODES, 1024, HD, HD, HD, HD);

    // kv[i][j] = sum_n k[n][i] v[n][j] (split-K atomic f32) + ksum role blocks
    mgemm<ACT_NONE, 0, 0, 0, 0, 1, 0, 1><<<gKV, blk, 0, stream>>>(
        kT, vT, nullptr, nullptr, kvfl, nullptr, nullptr, nullptr, ksuml,
        HD, KTP, KTP, HD, HD, 640);

    // cast8 (kvf->kvb) + z (q.ksum) merged
    cast_z_k<<<2628, blk, 0, stream>>>(kvfl, kvb, qb, ksuml, zb);

    // kvoT[j][i] = sum_m wo[m][j] kv[i][m]  (A=WoT, Bt=kvb)
    mgemm<ACT_NONE, 0, 0, 0, 1, 0, 0, 0><<<gS, blk, 0, stream>>>(
        WoT, kvb, nullptr, nullptr, nullptr, kvoT, nullptr, nullptr, nullptr,
        HD, HD, HD, HD, HD, HD);

    // h = (q @ kvo)*z + bo  -> hb bf16
    mgemm<ACT_NONE, 1, 1, 0, 1, 0, 0, 0><<<gG, blk, 0, stream>>>(
        qb, kvoT, bo + (long)l * HD, zb, nullptr, hb, nullptr, nullptr, nullptr,
        NNODES, HD, HD, HD, HD, HD);
    ln_res_k<<<2500, blk, 0, stream>>>(hg, hb, hgcat);
  }

  // ---- mix (K=1024 over hgcat) + cls ----
  mgemm<ACT_RELU, 1, 0, 0, 1, 0, 0, 0><<<gG, blk, 0, stream>>>(
      hgcat, WMT, b_mix, nullptr, nullptr, hmixb, nullptr, nullptr, nullptr,
      NNODES, 1024, 1024, HD, HD, 1024);
  mgemm<ACT_NONE, 1, 0, 1, 0, 0, 0, 0><<<gCls, blk, 0, stream>>>(
      hmixb, WCT, b_cls, nullptr, out, nullptr, nullptr, nullptr, nullptr,
      NNODES, HD, HD, OUTD, OUTD, HD);
}

// Round 12
// 610.025 us; speedup vs baseline: 1.0897x; 1.0897x over previous
//
#include <hip/hip_runtime.h>
#include <hip/hip_bf16.h>

// ================= problem constants =================
#define NNODES 10000
#define EEDGES 160000
#define HD     512
#define OUTD   128
#define NLAYERS 3
#define MP     10112           // NNODES padded to 79*128
#define KTP    10240           // transposed-layout node-dim pad (16*640)

#define ACT_NONE 0
#define ACT_RELU 1
#define ACT_ELU1 2

typedef __attribute__((ext_vector_type(8))) short bf16x8;
typedef __attribute__((ext_vector_type(4))) float f32x4;

__device__ __forceinline__ void gload16(const void* g, void* l) {
  __builtin_amdgcn_global_load_lds(
      (const __attribute__((address_space(1))) void*)g,
      (__attribute__((address_space(3))) void*)l, 16, 0, 0);
}

__device__ __forceinline__ void unp8(uint4 v, float* f) {
  const ushort* u = (const ushort*)&v;
#pragma unroll
  for (int j = 0; j < 8; ++j) f[j] = __uint_as_float(((unsigned)u[j]) << 16);
}

__device__ __forceinline__ ushort f2bu(float f) {
  __hip_bfloat16 h = __float2bfloat16(f);
  return *reinterpret_cast<ushort*>(&h);
}

__device__ __forceinline__ float elu1f(float v) {
  return (v > 0.f) ? (v + 1.0f) : __expf(v);
}

// ================= setup mega-kernel: init + castx + wtrans =================
// block ranges: [0,B0) init, [B0,B0+B1) castx, rest wtrans (17 z-slices).
// probe stays separate (flag zero must precede its atomicOr).
#define INIT_N (NNODES + 1 + 512 * 120 * 2)
#define B0 ((INIT_N + 255) / 256)
#define B1 ((int)((long)MP * HD / 8 / 256))
#define B2 (17 * 256)
__global__ __launch_bounds__(256) void setup_k(
    int* cnt, int* flag, __hip_bfloat16* kT, __hip_bfloat16* vT,
    const float* x, __hip_bfloat16* xb,
    const float* W_in, const float* Wq, const float* Wk, const float* Wv,
    const float* Wo, const float* W_gcn, const float* W_mix, const float* W_cls,
    __hip_bfloat16* WT, __hip_bfloat16* WMT, __hip_bfloat16* WCT)
{
  __shared__ float t[32][33];
  int b = blockIdx.x;
  if (b < B0) {
    int i = b * 256 + threadIdx.x;
    if (i < NNODES) { cnt[i] = 0; return; }
    i -= NNODES;
    if (i == 0) { *flag = 0; return; }
    i -= 1;
    if (i < 512 * 120 * 2) {
      int bb = i / (512 * 120);
      int r = (i % (512 * 120)) / 120;
      int c = (i % 120);
      uint* T = (uint*)(bb == 0 ? kT : vT);
      T[((long)r * KTP + NNODES) / 2 + c] = 0u;
    }
    return;
  }
  b -= B0;
  if (b < B1) {
    long i = (long)b * 256 + threadIdx.x;
    long base = i * 8;
    int row = (int)(base >> 9);
    ushort o[8];
    if (row < NNODES) {
      float4 a = *(const float4*)(x + base);
      float4 c = *(const float4*)(x + base + 4);
      float f[8] = {a.x, a.y, a.z, a.w, c.x, c.y, c.z, c.w};
#pragma unroll
      for (int j = 0; j < 8; ++j) o[j] = f2bu(f[j]);
    } else {
#pragma unroll
      for (int j = 0; j < 8; ++j) o[j] = 0;
    }
    *(uint4*)((ushort*)xb + base) = *(const uint4*)o;
    return;
  }
  b -= B1;
  // wtrans: z=0 W_in; 1..9 {Wq,Wk,Wv}; 10..12 Wo; 13 W_gcn; 14/15 W_mix->WMT; 16 W_cls->WCT
  int z = b >> 8;
  int rem = b & 255;
  int by = rem >> 4, bx = rem & 15;
  const float* src;
  __hip_bfloat16* out;
  int ldout = 512, koff = 0, ldsrc = 512;
  if (z == 0) { src = W_in; out = WT; }
  else if (z <= 9) {
    int l = (z - 1) / 3, w = (z - 1) % 3;
    src = (w == 0 ? Wq : w == 1 ? Wk : Wv) + (long)l * 262144;
    out = WT + (long)z * 262144;
  } else if (z <= 12) { src = Wo + (long)(z - 10) * 262144; out = WT + (long)z * 262144; }
  else if (z == 13) { src = W_gcn; out = WT + 13L * 262144; }
  else if (z <= 15) { src = W_mix + (long)(z - 14) * 262144; out = WMT; ldout = 1024; koff = (z - 14) * 512; }
  else {
    if (bx >= 4) return;              // W_cls has only 128 cols
    src = W_cls; out = WCT; ldsrc = 128;
  }
  int r0 = by * 32, c0 = bx * 32;
  int tx = threadIdx.x & 31, ty = threadIdx.x >> 5;
#pragma unroll
  for (int i = 0; i < 32; i += 8) t[ty + i][tx] = src[(long)(r0 + ty + i) * ldsrc + c0 + tx];
  __syncthreads();
#pragma unroll
  for (int i = 0; i < 32; i += 8)
    out[(long)(c0 + ty + i) * ldout + koff + r0 + tx] = __float2bfloat16(t[tx][ty + i]);
}

// ================= edge-index width probe (wave-coalesced atomic) =================
__global__ void probe_i64_k(const void* ei, int* flag, int E_) {
  int i = blockIdx.x * blockDim.x + threadIdx.x;
  bool nz = (i < E_) && (((const int*)ei)[2 * i + 1] != 0);
  unsigned long long m = __ballot(nz);
  if ((threadIdx.x & 63) == 0 && m) atomicOr(flag, 1);  // int32 layout detected
}
__device__ inline void load_edge(const void* ei, int is_i32, int e, int E_, int& s, int& d) {
  if (is_i32) { s = ((const int*)ei)[e]; d = ((const int*)ei)[E_ + e]; }
  else { s = (int)((const long long*)ei)[e]; d = (int)((const long long*)ei)[E_ + e]; }
}

// ================= bf16 MFMA GEMM (m97 structure, BK=64, XCD swizzle) =================
// C = epi(A[M,lda] @ Bt[N,ldb]^T), Bt row-major [N][K]. 128x128 tile, BK=64,
// 4 waves (2x2), wave tile 64x64. XOR bank-swizzle BOTH sides (rule #21).
// TQKV epilogue eps UNIONED with As/Bs.
template<int ACT, int HAS_BIAS, int HAS_SCALE, int OUTF, int OUTB, int TQKV>
__global__ __launch_bounds__(256) void mgemm(
    const __hip_bfloat16* __restrict__ A, const __hip_bfloat16* __restrict__ Bt,
    const float* __restrict__ bias, const float* __restrict__ rowscale,
    float* __restrict__ Cf, __hip_bfloat16* __restrict__ Cb,
    __hip_bfloat16* __restrict__ kTp, __hip_bfloat16* __restrict__ vTp,
    int M, int lda, int ldb, int ldc, int ldcb, int Ksz)
{
  __shared__ __align__(16) char smem[TQKV ? 35072 : 32768];

  // bijective XCD-aware swizzle (m204)
  int nwg = gridDim.x * gridDim.y;
  int orig = blockIdx.y * gridDim.x + blockIdx.x;
  int qq = nwg >> 3, rr8 = nwg & 7;
  int xcd = orig & 7, idx = orig >> 3;
  int wg = (xcd < rr8 ? xcd * (qq + 1) : rr8 * (qq + 1) + (xcd - rr8) * qq) + idx;
  int bx = wg % gridDim.x, by = wg / gridDim.x;

  int tid = threadIdx.x;
  int lane = tid & 63;
  int wave = tid >> 6;
  int wm = wave >> 1, wn = wave & 1;
  int row0 = by * 128;
  int col0 = bx * 128;
  int koff = blockIdx.z * Ksz;
  int srow8 = lane >> 3;
  int sb = ((lane & 7) * 16) ^ (srow8 << 4);  // pre-swizzled source byte

  f32x4 acc[4][4];
#pragma unroll
  for (int i = 0; i < 4; ++i)
#pragma unroll
    for (int j = 0; j < 4; ++j) acc[i][j] = f32x4{0.f, 0.f, 0.f, 0.f};

  int r16 = lane & 15;
  int kg = (lane >> 4) * 16;
  int rsw = (r16 & 7) << 4;

  for (int k0 = koff; k0 < koff + Ksz; k0 += 64) {
#pragma unroll
    for (int j = 0; j < 4; ++j) {
      int rbase = wave * 32 + j * 8;
      const char* ga = (const char*)(A + (long)(row0 + rbase + srow8) * lda + k0) + sb;
      gload16(ga, smem + rbase * 128);
      const char* gb = (const char*)(Bt + (long)(col0 + rbase + srow8) * ldb + k0) + sb;
      gload16(gb, smem + 16384 + rbase * 128);
    }
    __syncthreads();
#pragma unroll
    for (int s = 0; s < 2; ++s) {
      bf16x8 af[4], bfr[4];
      int off = ((s * 64 + kg) ^ rsw);
#pragma unroll
      for (int i = 0; i < 4; ++i)
        af[i] = *(const bf16x8*)(smem + (wm * 64 + i * 16 + r16) * 128 + off);
#pragma unroll
      for (int i = 0; i < 4; ++i)
        bfr[i] = *(const bf16x8*)(smem + 16384 + (wn * 64 + i * 16 + r16) * 128 + off);
#pragma unroll
      for (int i = 0; i < 4; ++i)
#pragma unroll
        for (int j = 0; j < 4; ++j)
          acc[i][j] = __builtin_amdgcn_mfma_f32_16x16x32_bf16(af[i], bfr[j], acc[i][j], 0, 0, 0);
    }
    __syncthreads();
  }

  // D frag: col = lane&15, row = (lane>>4)*4 + r  [m89/m91-verified]
  int rg = (lane >> 4) * 4;
  if (TQKV) {
    ushort* eps = (ushort*)smem;
    int colg = col0 + wn * 64;
    int g = colg >> 9;                // block-uniform (128-tile within 512-group)
    int cbase = col0 & 511;
#pragma unroll
    for (int i = 0; i < 4; ++i) {
#pragma unroll
      for (int j = 0; j < 4; ++j) {
        int c_l = wn * 64 + j * 16 + r16;
        int row_l = wm * 64 + i * 16 + rg;
        if (g == 0) {
#pragma unroll
          for (int r = 0; r < 4; ++r)
            eps[(row_l + r) * 136 + c_l] = f2bu(elu1f(acc[i][j][r]));
        } else {
          ushort4 o;
          o.x = f2bu(g == 1 ? elu1f(acc[i][j][0]) : acc[i][j][0]);
          o.y = f2bu(g == 1 ? elu1f(acc[i][j][1]) : acc[i][j][1]);
          o.z = f2bu(g == 1 ? elu1f(acc[i][j][2]) : acc[i][j][2]);
          o.w = f2bu(g == 1 ? elu1f(acc[i][j][3]) : acc[i][j][3]);
          *(ushort4*)&eps[c_l * 136 + row_l] = o;
        }
      }
    }
    __syncthreads();
    int l16 = tid & 15, cw = tid >> 4;
    if (g == 0) {
#pragma unroll
      for (int rr = cw; rr < 128; rr += 16) {
        int node = row0 + rr;
        if (node < NNODES)
          *(uint4*)((ushort*)Cb + (long)node * ldcb + cbase + l16 * 8) =
              *(const uint4*)&eps[rr * 136 + l16 * 8];
      }
    } else {
      ushort* T = (ushort*)(g == 1 ? kTp : vTp);
      int node0 = row0 + l16 * 8;
      if (node0 < NNODES) {
#pragma unroll
        for (int cc = cw; cc < 128; cc += 16)
          *(uint4*)(T + (long)(cbase + cc) * KTP + node0) = *(const uint4*)&eps[cc * 136 + l16 * 8];
      }
    }
    return;
  }
#pragma unroll
  for (int i = 0; i < 4; ++i) {
#pragma unroll
    for (int j = 0; j < 4; ++j) {
      int col = col0 + wn * 64 + j * 16 + r16;
#pragma unroll
      for (int r = 0; r < 4; ++r) {
        int row = row0 + wm * 64 + i * 16 + rg + r;
        if (row >= M) continue;
        float v = acc[i][j][r];
        if (HAS_SCALE) v *= rowscale[row];
        if (HAS_BIAS) v += bias[col];
        if (ACT == ACT_RELU) v = fmaxf(v, 0.f);
        if (ACT == ACT_ELU1) v = elu1f(v);
        if (OUTF) Cf[(long)row * ldc + col] = v;
        if (OUTB) Cb[(long)row * ldcb + col] = __float2bfloat16(v);
      }
    }
  }
}

// ============ small-GEMM kernel: 64x64 tiles (for 512x512 outputs) ============
// C = A[512,lda] @ Bt[512,ldb]^T, grid (8,8,Z). KSUM: z==gridDim.z-1 -> rowsum
// role over A's 512 rows into aux. Split slices write f32 partials
// Cf + z*262144 (no atomics, no init). OUTB: single-slice bf16 out to Cb.
template<int KSUM, int OUTB>
__global__ __launch_bounds__(256) void kvgemm_k(
    const __hip_bfloat16* __restrict__ A, const __hip_bfloat16* __restrict__ Bt,
    float* __restrict__ Cf, __hip_bfloat16* __restrict__ Cb,
    float* __restrict__ aux, int lda, int ldb, int Ksz)
{
  int lane = threadIdx.x & 63;
  int wave = threadIdx.x >> 6;
  if (KSUM && blockIdx.z == gridDim.z - 1) {
    // ksum role: 64 blocks x 4 waves x 2 rows = 512 rows of A
    int bi = blockIdx.y * 8 + blockIdx.x;
#pragma unroll
    for (int rr = 0; rr < 2; ++rr) {
      int i = bi * 8 + wave * 2 + rr;
      const ushort* kr = (const ushort*)A + (long)i * lda;
      float s = 0.f;
      for (int off = lane * 8; off < NNODES; off += 512) {
        uint4 v = *(const uint4*)(kr + off);
        float f[8]; unp8(v, f);
#pragma unroll
        for (int j = 0; j < 8; ++j) s += f[j];
      }
#pragma unroll
      for (int o = 32; o > 0; o >>= 1) s += __shfl_down(s, o);
      if (lane == 0) aux[i] = s;
    }
    return;
  }
  __shared__ __align__(16) char smem[16384];   // As 8KB + Bs 8KB (64 rows x 128B)
  int wm = wave >> 1, wn = wave & 1;
  int i0 = blockIdx.y * 64, j0 = blockIdx.x * 64;
  int koff = blockIdx.z * Ksz;
  int srow8 = lane >> 3;
  int sb = ((lane & 7) * 16) ^ (srow8 << 4);
  f32x4 acc[2][2];
#pragma unroll
  for (int i = 0; i < 2; ++i)
#pragma unroll
    for (int j = 0; j < 2; ++j) acc[i][j] = f32x4{0.f, 0.f, 0.f, 0.f};
  int r16 = lane & 15;
  int kg = (lane >> 4) * 16;
  int rsw = (r16 & 7) << 4;

  for (int k0 = koff; k0 < koff + Ksz; k0 += 64) {
#pragma unroll
    for (int j = 0; j < 2; ++j) {
      int rbase = wave * 16 + j * 8;
      const char* ga = (const char*)(A + (long)(i0 + rbase + srow8) * lda + k0) + sb;
      gload16(ga, smem + rbase * 128);
      const char* gb = (const char*)(Bt + (long)(j0 + rbase + srow8) * ldb + k0) + sb;
      gload16(gb, smem + 8192 + rbase * 128);
    }
    __syncthreads();
#pragma unroll
    for (int s = 0; s < 2; ++s) {
      bf16x8 af[2], bfr[2];
      int off = ((s * 64 + kg) ^ rsw);
#pragma unroll
      for (int i = 0; i < 2; ++i)
        af[i] = *(const bf16x8*)(smem + (wm * 32 + i * 16 + r16) * 128 + off);
#pragma unroll
      for (int i = 0; i < 2; ++i)
        bfr[i] = *(const bf16x8*)(smem + 8192 + (wn * 32 + i * 16 + r16) * 128 + off);
#pragma unroll
      for (int i = 0; i < 2; ++i)
#pragma unroll
        for (int j = 0; j < 2; ++j)
          acc[i][j] = __builtin_amdgcn_mfma_f32_16x16x32_bf16(af[i], bfr[j], acc[i][j], 0, 0, 0);
    }
    __syncthreads();
  }
  int rg = (lane >> 4) * 4;
  float* Cp = Cf + (long)blockIdx.z * 262144;
#pragma unroll
  for (int i = 0; i < 2; ++i) {
#pragma unroll
    for (int j = 0; j < 2; ++j) {
      int col = j0 + wn * 32 + j * 16 + r16;
#pragma unroll
      for (int r = 0; r < 4; ++r) {
        int row = i0 + wm * 32 + i * 16 + rg + r;
        if (OUTB) Cb[(long)row * 512 + col] = __float2bfloat16(acc[i][j][r]);
        else Cp[(long)row * 512 + col] = acc[i][j][r];
      }
    }
  }
}

// ===== merged: reduce16+cast (kvp->kvb, blocks 0..127) + z (blocks 128..2627) =====
__global__ __launch_bounds__(256) void cast_z_k(
    const float* __restrict__ kvp, __hip_bfloat16* __restrict__ kvb,
    const __hip_bfloat16* __restrict__ qb, const float* __restrict__ ksum,
    float* __restrict__ z)
{
  int b = blockIdx.x;
  if (b < 128) {
    long i = (long)b * 256 + threadIdx.x;   // 32768 groups of 8
    float acc8[8] = {};
#pragma unroll
    for (int s = 0; s < 16; ++s) {
      const float* sp = kvp + (long)s * 262144 + i * 8;
      float4 a = *(const float4*)sp, c = *(const float4*)(sp + 4);
      acc8[0] += a.x; acc8[1] += a.y; acc8[2] += a.z; acc8[3] += a.w;
      acc8[4] += c.x; acc8[5] += c.y; acc8[6] += c.z; acc8[7] += c.w;
    }
    ushort o[8];
#pragma unroll
    for (int j = 0; j < 8; ++j) o[j] = f2bu(acc8[j]);
    *(uint4*)((ushort*)kvb + i * 8) = *(const uint4*)o;
    return;
  }
  long gid = (long)(b - 128) * 256 + threadIdx.x;
  int row = (int)(gid >> 6), lane = (int)(gid & 63);
  if (row >= NNODES) return;
  uint4 qv = *(const uint4*)((const ushort*)qb + (long)row * HD + lane * 8);
  float f[8]; unp8(qv, f);
  const float* kk = ksum + lane * 8;
  float s = 0.f;
#pragma unroll
  for (int j = 0; j < 8; ++j) s += f[j] * kk[j];
#pragma unroll
  for (int o = 32; o > 0; o >>= 1) s += __shfl_down(s, o);
  if (lane == 0) z[row] = 1.0f / fmaxf(s, 1e-6f);
}

// ====== hg = LN(hg + h[bf16]); f32 -> hg, bf16 -> hgcat[:,0:512] (ld 1024) ======
__global__ __launch_bounds__(256) void ln_res_k(float* __restrict__ hg,
                                                const __hip_bfloat16* __restrict__ hb,
                                                __hip_bfloat16* __restrict__ hgcat) {
  int wid = (blockIdx.x * 256 + threadIdx.x) >> 6;
  int lane = threadIdx.x & 63;
  if (wid >= NNODES) return;
  float* row = hg + (long)wid * HD + lane * 8;
  uint4 hv = *(const uint4*)((const ushort*)hb + (long)wid * HD + lane * 8);
  float hf[8]; unp8(hv, hf);
  float4 p0 = *(const float4*)row, p1 = *(const float4*)(row + 4);
  float a[8] = {p0.x + hf[0], p0.y + hf[1], p0.z + hf[2], p0.w + hf[3],
                p1.x + hf[4], p1.y + hf[5], p1.z + hf[6], p1.w + hf[7]};
  float s = 0.f;
#pragma unroll
  for (int j = 0; j < 8; ++j) s += a[j];
#pragma unroll
  for (int o = 1; o < 64; o <<= 1) s += __shfl_xor(s, o);
  float mean = s * (1.0f / HD);
  float vs = 0.f;
#pragma unroll
  for (int j = 0; j < 8; ++j) { a[j] -= mean; vs += a[j] * a[j]; }
#pragma unroll
  for (int o = 1; o < 64; o <<= 1) vs += __shfl_xor(vs, o);
  float inv = rsqrtf(vs * (1.0f / HD) + 1e-5f);
  ushort ob[8];
#pragma unroll
  for (int j = 0; j < 8; ++j) { a[j] *= inv; ob[j] = f2bu(a[j]); }
  *(float4*)row = make_float4(a[0], a[1], a[2], a[3]);
  *(float4*)(row + 4) = make_float4(a[4], a[5], a[6], a[7]);
  *(uint4*)((ushort*)hgcat + (long)wid * 1024 + lane * 8) = *(const uint4*)ob;
}

// ================= GCN: CSR build + gather =================
__global__ void cnt_k(const void* ei, const int* flag, int* cnt, int E_) {
  int e = blockIdx.x * blockDim.x + threadIdx.x;
  if (e >= E_) return;
  int s, d; load_edge(ei, *flag, e, E_, s, d);
  atomicAdd(&cnt[d], 1);
}
__global__ __launch_bounds__(256) void scan_k(const int* __restrict__ cnt, int* __restrict__ rowptr,
                                              int* __restrict__ cursor, float* __restrict__ dis) {
  __shared__ int ps[256];
  int t = threadIdx.x;
  int lo = t * 40, hi = min(lo + 40, NNODES);
  int s = 0;
  for (int i = lo; i < hi; ++i) s += cnt[i];
  ps[t] = s;
  __syncthreads();
  for (int o = 1; o < 256; o <<= 1) {
    int v = (t >= o) ? ps[t - o] : 0;
    __syncthreads();
    ps[t] += v;
    __syncthreads();
  }
  int run = (t == 0) ? 0 : ps[t - 1];
  for (int i = lo; i < hi; ++i) {
    rowptr[i] = run; cursor[i] = run;
    dis[i] = rsqrtf((float)cnt[i] + 1.0f);
    run += cnt[i];
  }
  if (t == 255) rowptr[NNODES] = run;
}
__global__ void csrfill_k(const void* ei, const int* flag, int* cursor, int* csr, int E_) {
  int e = blockIdx.x * blockDim.x + threadIdx.x;
  if (e >= E_) return;
  int s, d; load_edge(ei, *flag, e, E_, s, d);
  int pos = atomicAdd(&cursor[d], 1);
  csr[pos] = s;
}
// wave per dst: h_graph[d] = relu(sum_src xw[src]*dis[s]*dis[d] + xw[d]*dis[d]^2 + b)
__global__ __launch_bounds__(256) void gcn_gather_k(
    const __hip_bfloat16* __restrict__ xwb, const int* __restrict__ rowptr,
    const int* __restrict__ csr, const float* __restrict__ dis,
    const float* __restrict__ bgcn, __hip_bfloat16* __restrict__ hgcat)
{
  int wid = (blockIdx.x * 256 + threadIdx.x) >> 6;
  int lane = threadIdx.x & 63;
  if (wid >= NNODES) return;
  int d = wid;
  float dd = dis[d];
  float acc[8], f[8], f2[8];
  uint4 v = *(const uint4*)((const ushort*)xwb + (long)d * HD + lane * 8);
  unp8(v, f);
#pragma unroll
  for (int j = 0; j < 8; ++j) acc[j] = f[j] * dd * dd;
  int e0 = rowptr[d], e1 = rowptr[d + 1];
  int e = e0;
  for (; e + 1 < e1; e += 2) {
    int s0 = csr[e], s1 = csr[e + 1];
    float w0 = dis[s0] * dd, w1 = dis[s1] * dd;
    uint4 xv0 = *(const uint4*)((const ushort*)xwb + (long)s0 * HD + lane * 8);
    uint4 xv1 = *(const uint4*)((const ushort*)xwb + (long)s1 * HD + lane * 8);
    unp8(xv0, f); unp8(xv1, f2);
#pragma unroll
    for (int j = 0; j < 8; ++j) acc[j] = fmaf(f[j], w0, fmaf(f2[j], w1, acc[j]));
  }
  if (e < e1) {
    int sN = csr[e];
    float w = dis[sN] * dd;
    uint4 xv = *(const uint4*)((const ushort*)xwb + (long)sN * HD + lane * 8);
    unp8(xv, f);
#pragma unroll
    for (int j = 0; j < 8; ++j) acc[j] = fmaf(f[j], w, acc[j]);
  }
  const float* bb = bgcn + lane * 8;
  ushort o[8];
#pragma unroll
  for (int j = 0; j < 8; ++j) o[j] = f2bu(fmaxf(acc[j] + bb[j], 0.f));
  *(uint4*)((ushort*)hgcat + (long)d * 1024 + 512 + lane * 8) = *(const uint4*)o;
}

// ================= host launcher =================
extern "C" void kernel_launch(void* const* d_in, const int* in_sizes, int n_in,
                              void* d_out, int out_size, void* d_ws, size_t ws_size,
                              hipStream_t stream) {
  const float* x     = (const float*)d_in[0];
  const void*  ei    = d_in[1];
  const float* W_in  = (const float*)d_in[2];
  const float* b_in  = (const float*)d_in[3];
  const float* Wq    = (const float*)d_in[4];
  const float* Wk    = (const float*)d_in[5];
  const float* Wv    = (const float*)d_in[6];
  const float* Wo    = (const float*)d_in[7];
  const float* bo    = (const float*)d_in[8];
  const float* W_gcn = (const float*)d_in[9];
  const float* b_gcn = (const float*)d_in[10];
  const float* W_mix = (const float*)d_in[11];
  const float* b_mix = (const float*)d_in[12];
  const float* W_cls = (const float*)d_in[13];
  const float* b_cls = (const float*)d_in[14];
  float* out = (float*)d_out;

  // ---- workspace layout (~100 MB; R1 proved >= 103.5 MB available) ----
  char* p = (char*)d_ws;
  __hip_bfloat16* WT  = (__hip_bfloat16*)p; p += 14L * 262144 * 2;
  __hip_bfloat16* WMT = (__hip_bfloat16*)p; p += 512L * 1024 * 2;
  __hip_bfloat16* WCT = (__hip_bfloat16*)p; p += 128L * 512 * 2;
  float* hg = (float*)p; p += (long)MP * HD * 4;
  __hip_bfloat16* hgcat = (__hip_bfloat16*)p; p += (long)MP * 1024 * 2;
  __hip_bfloat16* qb = (__hip_bfloat16*)p; p += (long)MP * HD * 2;   // xb/xwb alias
  __hip_bfloat16* vT = (__hip_bfloat16*)p; p += 512L * KTP * 2;
  __hip_bfloat16* kT = (__hip_bfloat16*)p; p += 512L * KTP * 2;     // hb/hmixb alias
  float* kvp = (float*)p; p += 16L * 512 * 512 * 4;                  // 16 MB partials
  __hip_bfloat16* kvb  = (__hip_bfloat16*)p; p += 512L * 512 * 2;
  __hip_bfloat16* kvoT = (__hip_bfloat16*)p; p += 512L * 512 * 2;
  float* ksum = (float*)p; p += 512 * 4;
  float* zb   = (float*)p; p += (long)MP * 4;
  int* cnt    = (int*)p; p += 40000;
  int* rowptr = (int*)p; p += 40016;
  int* cursor = (int*)p; p += 40000;
  float* dis  = (float*)p; p += 40000;
  int* csr    = (int*)p; p += 640000;
  int* flag   = (int*)p; p += 4;

  __hip_bfloat16* xb    = qb;     // input cast (dead after x0 GEMM)
  __hip_bfloat16* xwb   = qb;     // GCN xw (dead after gather)
  __hip_bfloat16* hb    = kT;     // attn h bf16 (kT dead after kv GEMM)
  __hip_bfloat16* hmixb = kT;     // mix out (after last layer)

  dim3 blk(256);
  dim3 gG(4, MP / 128);           // N=512 GEMMs
  dim3 gQKV(12, MP / 128);        // N=1536 fused
  dim3 gKV(8, 8, 17);             // kv: 64 tiles x 16 slices + ksum z-slice
  dim3 gS(8, 8, 1);               // 512x512 kvoT (64x64 tiles)
  dim3 gCls(1, MP / 128);

  // ---- setup: one mega-kernel (init+castx+wtrans), then probe ----
  setup_k<<<B0 + B1 + B2, blk, 0, stream>>>(cnt, flag, kT, vT, x, xb,
                                            W_in, Wq, Wk, Wv, Wo, W_gcn, W_mix, W_cls,
                                            WT, WMT, WCT);
  probe_i64_k<<<(EEDGES + 255) / 256, 256, 0, stream>>>(ei, flag, EEDGES);

  // x0 = relu(x@W_in+b): f32 -> hg, bf16 -> hgcat[:,0:512]
  mgemm<ACT_RELU, 1, 0, 1, 1, 0><<<gG, blk, 0, stream>>>(
      xb, WT, b_in, nullptr, hg, hgcat, nullptr, nullptr,
      NNODES, HD, HD, HD, 1024, HD);

  // ---- GCN branch ----
  mgemm<ACT_NONE, 0, 0, 0, 1, 0><<<gG, blk, 0, stream>>>(
      hgcat, WT + 13L * 262144, nullptr, nullptr, nullptr, xwb, nullptr, nullptr,
      NNODES, 1024, HD, HD, HD, HD);
  cnt_k<<<(EEDGES + 255) / 256, 256, 0, stream>>>(ei, flag, cnt, EEDGES);
  scan_k<<<1, 256, 0, stream>>>(cnt, rowptr, cursor, dis);
  csrfill_k<<<(EEDGES + 255) / 256, 256, 0, stream>>>(ei, flag, cursor, csr, EEDGES);
  gcn_gather_k<<<2500, blk, 0, stream>>>(xwb, rowptr, csr, dis, b_gcn, hgcat);

  // ---- attention layers ----
  for (int l = 0; l < NLAYERS; ++l) {
    const __hip_bfloat16* BtQKV = WT + (long)(1 + 3 * l) * 262144;   // [1536][512]
    const __hip_bfloat16* WoT   = WT + (long)(10 + l) * 262144;      // wo^T [512][512]

    // fused q/k/v: q->qb (elu1), k->kT[c][n] (elu1), v->vT[c][n]
    mgemm<ACT_NONE, 0, 0, 0, 0, 1><<<gQKV, blk, 0, stream>>>(
        hgcat, BtQKV, nullptr, nullptr, nullptr, qb, kT, vT,
        NNODES, 1024, HD, HD, HD, HD);

    // kv[i][j] = sum_n k[n][i] v[n][j]: 64 tiles x 16 slices -> f32 partials,
    // + ksum role (rowsum of kT). No atomics, no zero-init.
    kvgemm_k<1, 0><<<gKV, blk, 0, stream>>>(kT, vT, kvp, nullptr, ksum, KTP, KTP, 640);

    // reduce16+cast (kvp->kvb) + z (q.ksum) merged
    cast_z_k<<<2628, blk, 0, stream>>>(kvp, kvb, qb, ksum, zb);

    // kvoT[j][i] = sum_m wo[m][j] kv[i][m]  (A=WoT, Bt=kvb, 64x64 tiles)
    kvgemm_k<0, 1><<<gS, blk, 0, stream>>>(WoT, kvb, nullptr, kvoT, nullptr, 512, 512, 512);

    // h = (q @ kvo)*z + bo  -> hb bf16
    mgemm<ACT_NONE, 1, 1, 0, 1, 0><<<gG, blk, 0, stream>>>(
        qb, kvoT, bo + (long)l * HD, zb, nullptr, hb, nullptr, nullptr,
        NNODES, HD, HD, HD, HD, HD);
    ln_res_k<<<2500, blk, 0, stream>>>(hg, hb, hgcat);
  }

  // ---- mix (K=1024 over hgcat) + cls ----
  mgemm<ACT_RELU, 1, 0, 0, 1, 0><<<gG, blk, 0, stream>>>(
      hgcat, WMT, b_mix, nullptr, nullptr, hmixb, nullptr, nullptr,
      NNODES, 1024, 1024, HD, HD, 1024);
  mgemm<ACT_NONE, 1, 0, 1, 0, 0><<<gCls, blk, 0, stream>>>(
      hmixb, WCT, b_cls, nullptr, out, nullptr, nullptr, nullptr,
      NNODES, HD, HD, OUTD, OUTD, HD);
}